// Round 12
// baseline (344.343 us; speedup 1.0000x reference)
//
#include <hip/hip_runtime.h>
#include <hip/hip_bf16.h>
#include <math.h>

// CASSBlock fused: LN -> dir-select -> [gather -> fc1 -> dwconv3 -> gelu -> fc2] -> +x
// B=32 H=W=64 C=192 DIN=384 L=4096.
// Round 16 = Round 15 RESUBMIT (container infra failure, kernel never ran).
// R15: R14 base (fused 152.7us) + same restructure pattern applied to fc1:
//  - fc1: outer ks-slice, 6 independent B-loads per group, 12 INDEPENDENT
//    accumulators c0a[6]/c1a[6] (AGPRs). Was: per-nt chained 6-MFMA accs with
//    B-loads trickled in. Per-acc summation order unchanged (ks 0..5) = bit-exact.
//    (R14 proved this exact pattern on fc2: -15.5us, MfmaUtil 10->11.35.)
//  - fc2 own-half MFMAs moved between cg-writeback and exchange barrier:
//    pure-register work overlaps partner wave's LDS writes. Per-acc order
//    unchanged (own 0..5 then other 0..5).
// Launch bounds stay (256,4): min-waves hint steers compiler reg heuristics;
// every deviation (2/5) regressed. Guards: WRITE~99MB (spills), FETCH~77MB.
//
// ws layout (bytes):
//   xn   bf16 [32*4096*192]   @ 0          (50,331,648)
//   g    f32  [32*4096]       @ 50331648   (524,288)
//   w1s  bf16 [73728]         @ 50855936   (fragment-ordered fc1_w)
//   w2s  bf16 [73728]         @ 51003392   (fragment-ordered fc2_w)
//   dir  int  [32]            @ 51150848

typedef __bf16 bf16x8 __attribute__((ext_vector_type(8)));
typedef float f32x4 __attribute__((ext_vector_type(4)));
typedef __hip_bfloat16 hb;

#define XN_OFF   0
#define G_OFF    50331648
#define W1S_OFF  50855936
#define W2S_OFF  51003392
#define DIR_OFF  51150848

__device__ __forceinline__ float fast_gelu(float v) {
  // 0.5*v*(1+tanh(u)) with tanh(u) = 1 - 2/(1+exp(2u))  =>  v - v/(1+exp(2u))
  float u = v * (0.7978845608f + 0.0356774081f * v * v);
  float e = __expf(2.f * u);                    // inf for large u is fine
  float r = __builtin_amdgcn_rcpf(1.f + e);     // ->0 ; exp->0 => r->1 => result 0
  return v - v * r;
}

__device__ __forceinline__ unsigned short bf16bits(float f) {
  hb h = __float2bfloat16(f);
  return *reinterpret_cast<unsigned short*>(&h);
}

// ---------------- Kernel 1: LayerNorm + channel-mean g, with wshuf folded in ----------------
// blocks 0..8191: 16 pixels/block LN (writes xn bf16 + g). blocks 8192..8767: wshuf.
__global__ __launch_bounds__(256) void ln_wshuf_kernel(
    const float* __restrict__ x, const float* __restrict__ nw,
    const float* __restrict__ nb, hb* __restrict__ xn, float* __restrict__ g,
    const float* __restrict__ fc1_w, const float* __restrict__ fc2_w,
    hb* __restrict__ w1s, hb* __restrict__ w2s) {
  int t = threadIdx.x;
  if (blockIdx.x >= 8192) {
    // ---- weight shuffle to MFMA fragment order ----
    int idx = (blockIdx.x - 8192) * 256 + t;
    const float* w; hb* o; int K, KS, li;
    if (idx < 73728) { w = fc1_w; o = w1s; K = 192; KS = 6;  li = idx; }
    else             { w = fc2_w; o = w2s; K = 384; KS = 12; li = idx - 73728; }
    int j = li & 7, lane = (li >> 3) & 63, f = li >> 9;
    int ks = f % KS, nt = f / KS;
    int n = nt * 16 + (lane & 15);
    int k = ks * 32 + ((lane >> 4) << 3) + j;
    o[li] = __float2bfloat16(w[n * K + k]);
    return;
  }
  __shared__ float4 xt[768];          // 16 px * 48 f4 = 12288 B
  __shared__ unsigned int ytu[1536];  // 16 px * 96 dw (bf16 pairs) = 6144 B
  __shared__ float snw[192], snb[192];
  long pixbase = (long)blockIdx.x * 16;
  const float4* x4 = (const float4*)(x + pixbase * 192);
  #pragma unroll
  for (int i = 0; i < 3; i++) xt[t + i * 256] = x4[t + i * 256];
  if (t < 192) { snw[t] = nw[t]; snb[t] = nb[t]; }
  __syncthreads();

  int p = t >> 4, sub = t & 15;
  const float4* row = xt + p * 48 + sub * 3;
  float4 f0 = row[0], f1 = row[1], f2 = row[2];
  float v[12] = {f0.x, f0.y, f0.z, f0.w, f1.x, f1.y, f1.z, f1.w,
                 f2.x, f2.y, f2.z, f2.w};
  float s1 = 0.f, s2 = 0.f;
  #pragma unroll
  for (int i = 0; i < 12; i++) { s1 += v[i]; s2 += v[i] * v[i]; }
  #pragma unroll
  for (int off = 8; off; off >>= 1) {
    s1 += __shfl_xor(s1, off);
    s2 += __shfl_xor(s2, off);
  }
  float mu = s1 * (1.f / 192.f);
  float var = s2 * (1.f / 192.f) - mu * mu;
  float rstd = rsqrtf(var + 1e-5f);
  int c0 = sub * 12;
  float ys[12], gs = 0.f;
  #pragma unroll
  for (int i = 0; i < 12; i++) {
    ys[i] = (v[i] - mu) * rstd * snw[c0 + i] + snb[c0 + i];
    gs += ys[i];
  }
  #pragma unroll
  for (int off = 8; off; off >>= 1) gs += __shfl_xor(gs, off);
  if (sub == 0) g[pixbase + p] = gs * (1.f / 192.f);
  unsigned int* yo = ytu + p * 96 + sub * 6;
  #pragma unroll
  for (int i = 0; i < 6; i++)
    yo[i] = (unsigned int)bf16bits(ys[2 * i]) |
            ((unsigned int)bf16bits(ys[2 * i + 1]) << 16);
  __syncthreads();
  const float4* yt4 = (const float4*)ytu;
  float4* o4 = (float4*)(xn + pixbase * 192);
  o4[t] = yt4[t];
  if (t < 128) o4[t + 256] = yt4[t + 256];
}

// ---------------- Kernel 2: direction selector ----------------
__global__ __launch_bounds__(256) void sel_kernel(
    const float* __restrict__ g, const float* __restrict__ w1,
    const float* __restrict__ b1, const float* __restrict__ w2,
    const float* __restrict__ b2, int* __restrict__ dir) {
  __shared__ float gt[64][65];
  __shared__ float red[8];
  int b = blockIdx.x, t = threadIdx.x;
  const float* gb = g + (long)b * 4096;
  for (int i = t; i < 4096; i += 256) gt[i >> 6][i & 63] = gb[i];
  __syncthreads();
  float ah = 0.f, av = 0.f;
  for (int i = t; i < 3968; i += 256) {
    int r = i / 62, j = i - r * 62 + 1;
    float d = fabsf(gt[r][j + 1] - gt[r][j - 1]);
    if (r == 1 || r == 62) d *= 2.f;
    ah += d;
  }
  for (int i = t; i < 3968; i += 256) {
    int r = (i >> 6) + 1, c = i & 63;
    float d = fabsf(gt[r + 1][c] - gt[r - 1][c]);
    if (c == 1 || c == 62) d *= 2.f;
    av += d;
  }
  #pragma unroll
  for (int off = 32; off; off >>= 1) {
    ah += __shfl_xor(ah, off);
    av += __shfl_xor(av, off);
  }
  if ((t & 63) == 0) { red[(t >> 6) * 2] = ah; red[(t >> 6) * 2 + 1] = av; }
  __syncthreads();
  if (t == 0) {
    float sh = 0.f, sv = 0.f;
    for (int w = 0; w < 4; w++) { sh += red[w * 2]; sv += red[w * 2 + 1]; }
    sh *= (1.f / 4224.f);
    sv *= (1.f / 4224.f);
    float sc[4] = {sh, sv, 0.5f * (sh + sv), fabsf(sh - sv)};
    float hid[16];
    #pragma unroll
    for (int i = 0; i < 16; i++) {
      float a = b1[i];
      for (int k = 0; k < 4; k++) a += sc[k] * w1[i * 4 + k];
      hid[i] = fmaxf(a, 0.f);
    }
    float best = -1e30f; int bi = 0;
    for (int j = 0; j < 4; j++) {
      float a = b2[j];
      for (int i = 0; i < 16; i++) a += hid[i] * w2[j * 16 + i];
      if (a > best) { best = a; bi = j; }
    }
    dir[b] = bi;
  }
}

// ---------------- Kernel 3: fused seq block ----------------
// block = (mt, b): h rows l0-1 .. l0+30 (32 rows), outputs l0 .. l0+29.
#define SH_STR 196
__global__ __launch_bounds__(256, 4) void fused_kernel(
    const hb* __restrict__ xn, const hb* __restrict__ w1s, const hb* __restrict__ w2s,
    const float* __restrict__ fc1_b, const float* __restrict__ fc2_b,
    const float* __restrict__ conv_w, const float* __restrict__ conv_b,
    const float* __restrict__ x, const int* __restrict__ dirp,
    float* __restrict__ out) {
  __shared__ hb sH[2][32 * SH_STR];   // 25,088 B
  __shared__ float4 cvt[384];         //  6,144 B
  __shared__ float sB1[384];          //  1,536 B
  __shared__ float sB2[192];          //    768 B  => 33,792 B -> 4 blocks/CU

  int b = blockIdx.y, mt = blockIdx.x;
  int dir = dirp[b];
  int l0 = mt * 30;
  int t = threadIdx.x;

  for (int d = t; d < 384; d += 256) {
    cvt[d] = make_float4(conv_w[d * 3], conv_w[d * 3 + 1], conv_w[d * 3 + 2], conv_b[d]);
    sB1[d] = fc1_b[d];
  }
  if (t < 192) sB2[t] = fc2_b[t];

  int wave = t >> 6, lane = t & 63;
  int m16 = lane & 15, q = lane >> 4;
  const hb* xnb = xn + (long)b * 4096 * 192;

  // ---- fc1 A-frags: both 16-row tiles, rows tl*16+m16 (h-row), k full 192
  bf16x8 af[2][6];
  #pragma unroll
  for (int tl = 0; tl < 2; tl++) {
    int hr = tl * 16 + m16;
    int l = l0 - 1 + hr;
    int lc = min(max(l, 0), 4095);
    int src;
    if (dir == 0)      src = lc;
    else if (dir == 3) src = ((lc & 63) << 6) + 63 - (lc >> 6);
    else               src = ((lc & 63) << 6) + (lc >> 6);
    const bf16x8* ap = (const bf16x8*)(xnb + (long)src * 192) + q;
    #pragma unroll
    for (int ks = 0; ks < 6; ks++) af[tl][ks] = ap[ks * 4];
  }
  __syncthreads();  // sB1/cvt/sB2 staged

  // ---- fc1: outer ks, 6 independent B-loads per group, 12 independent accs
  // (R14's proven fc2 pattern). Per-acc summation order: ks 0..5 (bit-exact).
  {
    int buf = wave >> 1;
    int ntbase = wave * 6;
    f32x4 c0a[6], c1a[6];
    #pragma unroll
    for (int i = 0; i < 6; i++) {
      c0a[i] = (f32x4){0.f, 0.f, 0.f, 0.f};
      c1a[i] = (f32x4){0.f, 0.f, 0.f, 0.f};
    }
    const bf16x8* bpb = (const bf16x8*)w1s + (long)(ntbase * 6) * 64 + lane;
    #pragma unroll
    for (int ks = 0; ks < 6; ks++) {
      bf16x8 bf[6];
      #pragma unroll
      for (int i = 0; i < 6; i++) bf[i] = bpb[(i * 6 + ks) * 64];
      #pragma unroll
      for (int i = 0; i < 6; i++) {
        c0a[i] = __builtin_amdgcn_mfma_f32_16x16x32_bf16(af[0][ks], bf[i], c0a[i], 0, 0, 0);
        c1a[i] = __builtin_amdgcn_mfma_f32_16x16x32_bf16(af[1][ks], bf[i], c1a[i], 0, 0, 0);
      }
    }
    #pragma unroll
    for (int i = 0; i < 6; i++) {
      int nt = ntbase + i;
      float bias = sB1[nt * 16 + m16];
      int ncol = (nt - buf * 12) * 16 + m16;
      hb* s = &sH[buf][0];
      #pragma unroll
      for (int r = 0; r < 4; r++) {
        s[(q * 4 + r) * SH_STR + ncol]      = __float2bfloat16(c0a[i][r] + bias);
        s[(16 + q * 4 + r) * SH_STR + ncol] = __float2bfloat16(c1a[i][r] + bias);
      }
    }
  }
  __syncthreads();

  // ---- conv + gelu, DEDUPLICATED: wave (tile2, nth) computes only buffer nth's
  // 6 ks-slices for its 16 rows (exactly its own fc2 A-frag elements).
  int tile2 = wave & 1, nth = wave >> 1;
  int hr = tile2 * 16 + m16;
  int l_c = l0 - 1 + hr;
  bool hm_ok = (l_c >= 1);
  bool hp_ok = (l_c <= 4094);
  int rm = hr > 0 ? hr - 1 : 0;
  int rp = hr < 31 ? hr + 1 : 31;
  bf16x8 z8 = {};
  const hb* base = &sH[nth][0];
  bf16x8 cg[6];
  #pragma unroll
  for (int i = 0; i < 6; i++) {
    int col = i * 32 + q * 8;
    bf16x8 vm = *(const bf16x8*)(base + rm * SH_STR + col);
    bf16x8 vc = *(const bf16x8*)(base + hr * SH_STR + col);
    bf16x8 vp = *(const bf16x8*)(base + rp * SH_STR + col);
    if (!hm_ok) vm = z8;
    if (!hp_ok) vp = z8;
    int d0 = (nth * 6 + i) * 32 + q * 8;
    bf16x8 o;
    #pragma unroll
    for (int j = 0; j < 8; j++) {
      float4 cw = cvt[d0 + j];
      float s = fmaf((float)vm[j], cw.x,
                fmaf((float)vc[j], cw.y,
                fmaf((float)vp[j], cw.z, cw.w)));
      o[j] = (__bf16)fast_gelu(s);
    }
    cg[i] = o;
  }
  __syncthreads();  // all conv reads of sH complete

  // in-place writeback (gelu output occupies same coords as conv input)
  {
    hb* wb = &sH[nth][0];
    #pragma unroll
    for (int i = 0; i < 6; i++)
      *(bf16x8*)(wb + hr * SH_STR + i * 32 + q * 8) = cg[i];
  }

  // ---- fc2 own half (cg in regs, no sH reads) BEFORE the exchange barrier:
  // overlaps the partner wave's LDS writeback. Per-acc order: own 0..5.
  f32x4 acc[6];
  #pragma unroll
  for (int i = 0; i < 6; i++) acc[i] = (f32x4){0.f, 0.f, 0.f, 0.f};
  const bf16x8* bp2 = (const bf16x8*)w2s + lane;
  #pragma unroll
  for (int i = 0; i < 6; i++) {
    int kk = nth * 6 + i;
    #pragma unroll
    for (int i2 = 0; i2 < 6; i2++) {
      int nt2 = nth * 6 + i2;
      acc[i2] = __builtin_amdgcn_mfma_f32_16x16x32_bf16(
          cg[i], bp2[((long)nt2 * 12 + kk) * 64], acc[i2], 0, 0, 0);
    }
  }
  __syncthreads();  // exchange complete

  // ---- fc2 other half from LDS at point of use. Per-acc order: other 0..5.
  {
    const hb* ob = &sH[nth ^ 1][0];
    #pragma unroll
    for (int i = 0; i < 6; i++) {
      int kk = (nth ^ 1) * 6 + i;
      bf16x8 a = *(const bf16x8*)(ob + hr * SH_STR + i * 32 + q * 8);
      #pragma unroll
      for (int i2 = 0; i2 < 6; i2++) {
        int nt2 = nth * 6 + i2;
        acc[i2] = __builtin_amdgcn_mfma_f32_16x16x32_bf16(
            a, bp2[((long)nt2 * 12 + kk) * 64], acc[i2], 0, 0, 0);
      }
    }
  }

  // ---- epilogue: out = x + acc + fc2_b for valid rows (hr_r in [1,30], l <= 4095)
  #pragma unroll
  for (int i2 = 0; i2 < 6; i2++) {
    int c = (nth * 6 + i2) * 16 + m16;
    float bias = sB2[c];
    #pragma unroll
    for (int r = 0; r < 4; r++) {
      int hr_r = tile2 * 16 + q * 4 + r;
      int l_r = l0 - 1 + hr_r;
      if (hr_r >= 1 && hr_r <= 30 && l_r <= 4095) {
        long idx = ((long)b * 4096 + l_r) * 192 + c;
        out[idx] = x[idx] + acc[i2][r] + bias;
      }
    }
  }
}

extern "C" void kernel_launch(void* const* d_in, const int* in_sizes, int n_in,
                              void* d_out, int out_size, void* d_ws, size_t ws_size,
                              hipStream_t stream) {
  const float* x      = (const float*)d_in[0];
  const float* norm_w = (const float*)d_in[1];
  const float* norm_b = (const float*)d_in[2];
  const float* sel_w1 = (const float*)d_in[3];
  const float* sel_b1 = (const float*)d_in[4];
  const float* sel_w2 = (const float*)d_in[5];
  const float* sel_b2 = (const float*)d_in[6];
  const float* fc1_w  = (const float*)d_in[7];
  const float* fc1_b  = (const float*)d_in[8];
  const float* conv_w = (const float*)d_in[9];
  const float* conv_b = (const float*)d_in[10];
  const float* fc2_w  = (const float*)d_in[11];
  const float* fc2_b  = (const float*)d_in[12];
  float* out = (float*)d_out;
  char* ws = (char*)d_ws;

  hb* xn    = (hb*)(ws + XN_OFF);
  float* g  = (float*)(ws + G_OFF);
  hb* w1s   = (hb*)(ws + W1S_OFF);
  hb* w2s   = (hb*)(ws + W2S_OFF);
  int* dir  = (int*)(ws + DIR_OFF);

  ln_wshuf_kernel<<<8768, 256, 0, stream>>>(x, norm_w, norm_b, xn, g,
                                            fc1_w, fc2_w, w1s, w2s);
  sel_kernel<<<32, 256, 0, stream>>>(g, sel_w1, sel_b1, sel_w2, sel_b2, dir);
  dim3 gg(137, 32);
  fused_kernel<<<gg, 256, 0, stream>>>(xn, w1s, w2s, fc1_b, fc2_b,
                                       conv_w, conv_b, x, dir, out);
}

// Round 13
// 335.783 us; speedup vs baseline: 1.0255x; 1.0255x over previous
//
#include <hip/hip_runtime.h>
#include <hip/hip_bf16.h>
#include <math.h>

// CASSBlock fused: LN -> dir-select -> [gather -> fc1 -> dwconv3 -> gelu -> fc2] -> +x
// B=32 H=W=64 C=192 DIN=384 L=4096.
// Round 17: R16 A/B decomposition. R15/16 (fc1 batch-restructure + fc2 hoist)
// regressed 152.7->161.3: at the hard 64-VGPR ceiling under (256,4), fc1's
// bf[6]+12-acc pattern can't pipeline (needs ~120 live regs) -> serialization.
// REVERT fc1 to R14's chained form (1-2 B-frags live, fits budget).
// KEEP only the fc2 own-half hoist (pure-register MFMAs between cg-writeback and
// exchange barrier; overlaps partner waves' LDS writes; zero added reg pressure).
// Per-acc summation order unchanged everywhere (own 0..5 then other 0..5).
// Lesson bank: compiler pins VGPR=64 under (256,4) regardless of code shape;
// restructures only pay when they REDUCE net live state (R14 fc2: -24 regs).
//
// ws layout (bytes):
//   xn   bf16 [32*4096*192]   @ 0          (50,331,648)
//   g    f32  [32*4096]       @ 50331648   (524,288)
//   w1s  bf16 [73728]         @ 50855936   (fragment-ordered fc1_w)
//   w2s  bf16 [73728]         @ 51003392   (fragment-ordered fc2_w)
//   dir  int  [32]            @ 51150848

typedef __bf16 bf16x8 __attribute__((ext_vector_type(8)));
typedef float f32x4 __attribute__((ext_vector_type(4)));
typedef __hip_bfloat16 hb;

#define XN_OFF   0
#define G_OFF    50331648
#define W1S_OFF  50855936
#define W2S_OFF  51003392
#define DIR_OFF  51150848

__device__ __forceinline__ float fast_gelu(float v) {
  // 0.5*v*(1+tanh(u)) with tanh(u) = 1 - 2/(1+exp(2u))  =>  v - v/(1+exp(2u))
  float u = v * (0.7978845608f + 0.0356774081f * v * v);
  float e = __expf(2.f * u);                    // inf for large u is fine
  float r = __builtin_amdgcn_rcpf(1.f + e);     // ->0 ; exp->0 => r->1 => result 0
  return v - v * r;
}

__device__ __forceinline__ unsigned short bf16bits(float f) {
  hb h = __float2bfloat16(f);
  return *reinterpret_cast<unsigned short*>(&h);
}

// ---------------- Kernel 1: LayerNorm + channel-mean g, with wshuf folded in ----------------
// blocks 0..8191: 16 pixels/block LN (writes xn bf16 + g). blocks 8192..8767: wshuf.
__global__ __launch_bounds__(256) void ln_wshuf_kernel(
    const float* __restrict__ x, const float* __restrict__ nw,
    const float* __restrict__ nb, hb* __restrict__ xn, float* __restrict__ g,
    const float* __restrict__ fc1_w, const float* __restrict__ fc2_w,
    hb* __restrict__ w1s, hb* __restrict__ w2s) {
  int t = threadIdx.x;
  if (blockIdx.x >= 8192) {
    // ---- weight shuffle to MFMA fragment order ----
    int idx = (blockIdx.x - 8192) * 256 + t;
    const float* w; hb* o; int K, KS, li;
    if (idx < 73728) { w = fc1_w; o = w1s; K = 192; KS = 6;  li = idx; }
    else             { w = fc2_w; o = w2s; K = 384; KS = 12; li = idx - 73728; }
    int j = li & 7, lane = (li >> 3) & 63, f = li >> 9;
    int ks = f % KS, nt = f / KS;
    int n = nt * 16 + (lane & 15);
    int k = ks * 32 + ((lane >> 4) << 3) + j;
    o[li] = __float2bfloat16(w[n * K + k]);
    return;
  }
  __shared__ float4 xt[768];          // 16 px * 48 f4 = 12288 B
  __shared__ unsigned int ytu[1536];  // 16 px * 96 dw (bf16 pairs) = 6144 B
  __shared__ float snw[192], snb[192];
  long pixbase = (long)blockIdx.x * 16;
  const float4* x4 = (const float4*)(x + pixbase * 192);
  #pragma unroll
  for (int i = 0; i < 3; i++) xt[t + i * 256] = x4[t + i * 256];
  if (t < 192) { snw[t] = nw[t]; snb[t] = nb[t]; }
  __syncthreads();

  int p = t >> 4, sub = t & 15;
  const float4* row = xt + p * 48 + sub * 3;
  float4 f0 = row[0], f1 = row[1], f2 = row[2];
  float v[12] = {f0.x, f0.y, f0.z, f0.w, f1.x, f1.y, f1.z, f1.w,
                 f2.x, f2.y, f2.z, f2.w};
  float s1 = 0.f, s2 = 0.f;
  #pragma unroll
  for (int i = 0; i < 12; i++) { s1 += v[i]; s2 += v[i] * v[i]; }
  #pragma unroll
  for (int off = 8; off; off >>= 1) {
    s1 += __shfl_xor(s1, off);
    s2 += __shfl_xor(s2, off);
  }
  float mu = s1 * (1.f / 192.f);
  float var = s2 * (1.f / 192.f) - mu * mu;
  float rstd = rsqrtf(var + 1e-5f);
  int c0 = sub * 12;
  float ys[12], gs = 0.f;
  #pragma unroll
  for (int i = 0; i < 12; i++) {
    ys[i] = (v[i] - mu) * rstd * snw[c0 + i] + snb[c0 + i];
    gs += ys[i];
  }
  #pragma unroll
  for (int off = 8; off; off >>= 1) gs += __shfl_xor(gs, off);
  if (sub == 0) g[pixbase + p] = gs * (1.f / 192.f);
  unsigned int* yo = ytu + p * 96 + sub * 6;
  #pragma unroll
  for (int i = 0; i < 6; i++)
    yo[i] = (unsigned int)bf16bits(ys[2 * i]) |
            ((unsigned int)bf16bits(ys[2 * i + 1]) << 16);
  __syncthreads();
  const float4* yt4 = (const float4*)ytu;
  float4* o4 = (float4*)(xn + pixbase * 192);
  o4[t] = yt4[t];
  if (t < 128) o4[t + 256] = yt4[t + 256];
}

// ---------------- Kernel 2: direction selector ----------------
__global__ __launch_bounds__(256) void sel_kernel(
    const float* __restrict__ g, const float* __restrict__ w1,
    const float* __restrict__ b1, const float* __restrict__ w2,
    const float* __restrict__ b2, int* __restrict__ dir) {
  __shared__ float gt[64][65];
  __shared__ float red[8];
  int b = blockIdx.x, t = threadIdx.x;
  const float* gb = g + (long)b * 4096;
  for (int i = t; i < 4096; i += 256) gt[i >> 6][i & 63] = gb[i];
  __syncthreads();
  float ah = 0.f, av = 0.f;
  for (int i = t; i < 3968; i += 256) {
    int r = i / 62, j = i - r * 62 + 1;
    float d = fabsf(gt[r][j + 1] - gt[r][j - 1]);
    if (r == 1 || r == 62) d *= 2.f;
    ah += d;
  }
  for (int i = t; i < 3968; i += 256) {
    int r = (i >> 6) + 1, c = i & 63;
    float d = fabsf(gt[r + 1][c] - gt[r - 1][c]);
    if (c == 1 || c == 62) d *= 2.f;
    av += d;
  }
  #pragma unroll
  for (int off = 32; off; off >>= 1) {
    ah += __shfl_xor(ah, off);
    av += __shfl_xor(av, off);
  }
  if ((t & 63) == 0) { red[(t >> 6) * 2] = ah; red[(t >> 6) * 2 + 1] = av; }
  __syncthreads();
  if (t == 0) {
    float sh = 0.f, sv = 0.f;
    for (int w = 0; w < 4; w++) { sh += red[w * 2]; sv += red[w * 2 + 1]; }
    sh *= (1.f / 4224.f);
    sv *= (1.f / 4224.f);
    float sc[4] = {sh, sv, 0.5f * (sh + sv), fabsf(sh - sv)};
    float hid[16];
    #pragma unroll
    for (int i = 0; i < 16; i++) {
      float a = b1[i];
      for (int k = 0; k < 4; k++) a += sc[k] * w1[i * 4 + k];
      hid[i] = fmaxf(a, 0.f);
    }
    float best = -1e30f; int bi = 0;
    for (int j = 0; j < 4; j++) {
      float a = b2[j];
      for (int i = 0; i < 16; i++) a += hid[i] * w2[j * 16 + i];
      if (a > best) { best = a; bi = j; }
    }
    dir[b] = bi;
  }
}

// ---------------- Kernel 3: fused seq block ----------------
// block = (mt, b): h rows l0-1 .. l0+30 (32 rows), outputs l0 .. l0+29.
#define SH_STR 196
__global__ __launch_bounds__(256, 4) void fused_kernel(
    const hb* __restrict__ xn, const hb* __restrict__ w1s, const hb* __restrict__ w2s,
    const float* __restrict__ fc1_b, const float* __restrict__ fc2_b,
    const float* __restrict__ conv_w, const float* __restrict__ conv_b,
    const float* __restrict__ x, const int* __restrict__ dirp,
    float* __restrict__ out) {
  __shared__ hb sH[2][32 * SH_STR];   // 25,088 B
  __shared__ float4 cvt[384];         //  6,144 B
  __shared__ float sB1[384];          //  1,536 B
  __shared__ float sB2[192];          //    768 B  => 33,792 B -> 4 blocks/CU

  int b = blockIdx.y, mt = blockIdx.x;
  int dir = dirp[b];
  int l0 = mt * 30;
  int t = threadIdx.x;

  for (int d = t; d < 384; d += 256) {
    cvt[d] = make_float4(conv_w[d * 3], conv_w[d * 3 + 1], conv_w[d * 3 + 2], conv_b[d]);
    sB1[d] = fc1_b[d];
  }
  if (t < 192) sB2[t] = fc2_b[t];

  int wave = t >> 6, lane = t & 63;
  int m16 = lane & 15, q = lane >> 4;
  const hb* xnb = xn + (long)b * 4096 * 192;

  // ---- fc1 A-frags: both 16-row tiles, rows tl*16+m16 (h-row), k full 192
  bf16x8 af[2][6];
  #pragma unroll
  for (int tl = 0; tl < 2; tl++) {
    int hr = tl * 16 + m16;
    int l = l0 - 1 + hr;
    int lc = min(max(l, 0), 4095);
    int src;
    if (dir == 0)      src = lc;
    else if (dir == 3) src = ((lc & 63) << 6) + 63 - (lc >> 6);
    else               src = ((lc & 63) << 6) + (lc >> 6);
    const bf16x8* ap = (const bf16x8*)(xnb + (long)src * 192) + q;
    #pragma unroll
    for (int ks = 0; ks < 6; ks++) af[tl][ks] = ap[ks * 4];
  }
  __syncthreads();  // sB1/cvt/sB2 staged

  // ---- fc1 (R14 chained form): wave w handles nt = 6w..6w+5 for both tiles;
  // B loaded once, used 2x. Fits the 64-VGPR budget (1-2 B-frags live).
  {
    int buf = wave >> 1;
    int ntbase = wave * 6;
    #pragma unroll
    for (int i = 0; i < 6; i++) {
      int nt = ntbase + i;
      const bf16x8* bp = (const bf16x8*)w1s + (long)(nt * 6) * 64 + lane;
      f32x4 c0 = {0.f, 0.f, 0.f, 0.f}, c1 = {0.f, 0.f, 0.f, 0.f};
      #pragma unroll
      for (int ks = 0; ks < 6; ks++) {
        bf16x8 bf = bp[ks * 64];
        c0 = __builtin_amdgcn_mfma_f32_16x16x32_bf16(af[0][ks], bf, c0, 0, 0, 0);
        c1 = __builtin_amdgcn_mfma_f32_16x16x32_bf16(af[1][ks], bf, c1, 0, 0, 0);
      }
      float bias = sB1[nt * 16 + m16];
      int ncol = (nt - buf * 12) * 16 + m16;
      hb* s = &sH[buf][0];
      #pragma unroll
      for (int r = 0; r < 4; r++) {
        s[(q * 4 + r) * SH_STR + ncol]      = __float2bfloat16(c0[r] + bias);
        s[(16 + q * 4 + r) * SH_STR + ncol] = __float2bfloat16(c1[r] + bias);
      }
    }
  }
  __syncthreads();

  // ---- conv + gelu, DEDUPLICATED: wave (tile2, nth) computes only buffer nth's
  // 6 ks-slices for its 16 rows (exactly its own fc2 A-frag elements).
  int tile2 = wave & 1, nth = wave >> 1;
  int hr = tile2 * 16 + m16;
  int l_c = l0 - 1 + hr;
  bool hm_ok = (l_c >= 1);
  bool hp_ok = (l_c <= 4094);
  int rm = hr > 0 ? hr - 1 : 0;
  int rp = hr < 31 ? hr + 1 : 31;
  bf16x8 z8 = {};
  const hb* base = &sH[nth][0];
  bf16x8 cg[6];
  #pragma unroll
  for (int i = 0; i < 6; i++) {
    int col = i * 32 + q * 8;
    bf16x8 vm = *(const bf16x8*)(base + rm * SH_STR + col);
    bf16x8 vc = *(const bf16x8*)(base + hr * SH_STR + col);
    bf16x8 vp = *(const bf16x8*)(base + rp * SH_STR + col);
    if (!hm_ok) vm = z8;
    if (!hp_ok) vp = z8;
    int d0 = (nth * 6 + i) * 32 + q * 8;
    bf16x8 o;
    #pragma unroll
    for (int j = 0; j < 8; j++) {
      float4 cw = cvt[d0 + j];
      float s = fmaf((float)vm[j], cw.x,
                fmaf((float)vc[j], cw.y,
                fmaf((float)vp[j], cw.z, cw.w)));
      o[j] = (__bf16)fast_gelu(s);
    }
    cg[i] = o;
  }
  __syncthreads();  // all conv reads of sH complete

  // in-place writeback (gelu output occupies same coords as conv input)
  {
    hb* wb = &sH[nth][0];
    #pragma unroll
    for (int i = 0; i < 6; i++)
      *(bf16x8*)(wb + hr * SH_STR + i * 32 + q * 8) = cg[i];
  }

  // ---- fc2 own half (cg in regs, no sH reads) BEFORE the exchange barrier:
  // overlaps the partner wave's LDS writeback. Per-acc order: own 0..5.
  f32x4 acc[6];
  #pragma unroll
  for (int i = 0; i < 6; i++) acc[i] = (f32x4){0.f, 0.f, 0.f, 0.f};
  const bf16x8* bp2 = (const bf16x8*)w2s + lane;
  #pragma unroll
  for (int i = 0; i < 6; i++) {
    int kk = nth * 6 + i;
    #pragma unroll
    for (int i2 = 0; i2 < 6; i2++) {
      int nt2 = nth * 6 + i2;
      acc[i2] = __builtin_amdgcn_mfma_f32_16x16x32_bf16(
          cg[i], bp2[((long)nt2 * 12 + kk) * 64], acc[i2], 0, 0, 0);
    }
  }
  __syncthreads();  // exchange complete

  // ---- fc2 other half from LDS at point of use. Per-acc order: other 0..5.
  {
    const hb* ob = &sH[nth ^ 1][0];
    #pragma unroll
    for (int i = 0; i < 6; i++) {
      int kk = (nth ^ 1) * 6 + i;
      bf16x8 a = *(const bf16x8*)(ob + hr * SH_STR + i * 32 + q * 8);
      #pragma unroll
      for (int i2 = 0; i2 < 6; i2++) {
        int nt2 = nth * 6 + i2;
        acc[i2] = __builtin_amdgcn_mfma_f32_16x16x32_bf16(
            a, bp2[((long)nt2 * 12 + kk) * 64], acc[i2], 0, 0, 0);
      }
    }
  }

  // ---- epilogue: out = x + acc + fc2_b for valid rows (hr_r in [1,30], l <= 4095)
  #pragma unroll
  for (int i2 = 0; i2 < 6; i2++) {
    int c = (nth * 6 + i2) * 16 + m16;
    float bias = sB2[c];
    #pragma unroll
    for (int r = 0; r < 4; r++) {
      int hr_r = tile2 * 16 + q * 4 + r;
      int l_r = l0 - 1 + hr_r;
      if (hr_r >= 1 && hr_r <= 30 && l_r <= 4095) {
        long idx = ((long)b * 4096 + l_r) * 192 + c;
        out[idx] = x[idx] + acc[i2][r] + bias;
      }
    }
  }
}

extern "C" void kernel_launch(void* const* d_in, const int* in_sizes, int n_in,
                              void* d_out, int out_size, void* d_ws, size_t ws_size,
                              hipStream_t stream) {
  const float* x      = (const float*)d_in[0];
  const float* norm_w = (const float*)d_in[1];
  const float* norm_b = (const float*)d_in[2];
  const float* sel_w1 = (const float*)d_in[3];
  const float* sel_b1 = (const float*)d_in[4];
  const float* sel_w2 = (const float*)d_in[5];
  const float* sel_b2 = (const float*)d_in[6];
  const float* fc1_w  = (const float*)d_in[7];
  const float* fc1_b  = (const float*)d_in[8];
  const float* conv_w = (const float*)d_in[9];
  const float* conv_b = (const float*)d_in[10];
  const float* fc2_w  = (const float*)d_in[11];
  const float* fc2_b  = (const float*)d_in[12];
  float* out = (float*)d_out;
  char* ws = (char*)d_ws;

  hb* xn    = (hb*)(ws + XN_OFF);
  float* g  = (float*)(ws + G_OFF);
  hb* w1s   = (hb*)(ws + W1S_OFF);
  hb* w2s   = (hb*)(ws + W2S_OFF);
  int* dir  = (int*)(ws + DIR_OFF);

  ln_wshuf_kernel<<<8768, 256, 0, stream>>>(x, norm_w, norm_b, xn, g,
                                            fc1_w, fc2_w, w1s, w2s);
  sel_kernel<<<32, 256, 0, stream>>>(g, sel_w1, sel_b1, sel_w2, sel_b2, dir);
  dim3 gg(137, 32);
  fused_kernel<<<gg, 256, 0, stream>>>(xn, w1s, w2s, fc1_b, fc2_b,
                                       conv_w, conv_b, x, dir, out);
}